// Round 1
// baseline (254.137 us; speedup 1.0000x reference)
//
#include <hip/hip_runtime.h>
#include <hip/hip_bf16.h>
#include <stdint.h>

#define AS_GLOBAL __attribute__((address_space(1)))
#define AS_LDS    __attribute__((address_space(3)))

typedef __attribute__((ext_vector_type(8))) short  bf16x8;
typedef __attribute__((ext_vector_type(4))) float  f32x4;
typedef __attribute__((ext_vector_type(4))) short  s16x4;
typedef __attribute__((ext_vector_type(8))) short  s16x8;

__device__ __forceinline__ void gload_lds16(const void* g, void* l) {
    __builtin_amdgcn_global_load_lds((AS_GLOBAL const void*)g, (AS_LDS void*)l, 16, 0, 0);
}

// Cast 8 fp32 -> 8 bf16 (one 16B store), pair index p into region (s,d).
__device__ __forceinline__ void cast_pair(const float* __restrict__ s,
                                          __hip_bfloat16* __restrict__ d, long p) {
    f32x4 a = ((const f32x4*)s)[p * 2];
    f32x4 b = ((const f32x4*)s)[p * 2 + 1];
    union { s16x8 p8; __hip_bfloat16 h[8]; } u;
    u.h[0] = __float2bfloat16(a.x); u.h[1] = __float2bfloat16(a.y);
    u.h[2] = __float2bfloat16(a.z); u.h[3] = __float2bfloat16(a.w);
    u.h[4] = __float2bfloat16(b.x); u.h[5] = __float2bfloat16(b.y);
    u.h[6] = __float2bfloat16(b.z); u.h[7] = __float2bfloat16(b.w);
    ((s16x8*)d)[p] = u.p8;
}

// castA: x (262144 pairs) + W1 (1048576 pairs) = 1310720 pairs; 1280 blocks x 256 x 4 iters.
__global__ void cast_a_k(const float* __restrict__ x,  __hip_bfloat16* __restrict__ xb,
                         const float* __restrict__ W1, __hip_bfloat16* __restrict__ W1b) {
    const long nx = 262144, ntot = 1310720, stride = 1280 * 256;
    long t = (long)blockIdx.x * 256 + threadIdx.x;
    for (long p = t; p < ntot; p += stride) {
        if (p < nx) cast_pair(x, xb, p);
        else        cast_pair(W1, W1b, p - nx);
    }
}

// Split-K GEMM: P[z][M,N] = bf16( A[M,k0:k1] @ B[N,k0:k1]^T ).
// grid = (N/128, M/128, CP + S), CP = FUSECAST leading cast planes (z < CP).
// R1 changes vs 250.6us baseline:
//  * Double-buffered LDS (T3-minimum 2-phase): stage tile t+1 BEFORE compute of
//    tile t; one barrier per tile. 64KB LDS -> launch_bounds(256,2) = 2 blk/CU.
//  * XCD-chunked (bn,bm) swizzle per z-plane: each XCD owns a (Gx/8)bn x Gy bm
//    rectangle -> A/B panel footprint ~3MB fits the 4MB per-XCD L2.
// 128x128 tile, BK=64, 4 waves, 4x4 16x16x32 MFMA, XOR-swizzled LDS
// (conflict-free, verified R4-R7 of prior session): granule g of row r at slot g^(r&7).
template <int FUSECAST>
__global__ __launch_bounds__(256, 2)
void gemm_btk(const __hip_bfloat16* __restrict__ A,
              const __hip_bfloat16* __restrict__ Bm,
              __hip_bfloat16* __restrict__ P,
              const int M, const int N, const int kchunk, const int S,
              const float* __restrict__ cs1, __hip_bfloat16* __restrict__ cd1, const long cn1,
              const float* __restrict__ cs2, __hip_bfloat16* __restrict__ cd2, const long cn2)
{
    __shared__ __hip_bfloat16 As[2][128 * 64];
    __shared__ __hip_bfloat16 Bs[2][128 * 64];

    const int tid = threadIdx.x;
    int bn = blockIdx.x, bm = blockIdx.y;
    const int z = blockIdx.z;

    if (FUSECAST && z < FUSECAST) {
        const long nb     = (long)gridDim.x * gridDim.y;
        const long stride = FUSECAST * nb * 256;
        long t = ((long)z * nb + (long)bm * gridDim.x + bn) * 256 + tid;
        const long ntot = cn1 + cn2;
        for (long p = t; p < ntot; p += stride) {
            if (p < cn1) cast_pair(cs1, cd1, p);
            else         cast_pair(cs2, cd2, p - cn1);
        }
        return;
    }
    const int kz = z - FUSECAST;

    // XCD-chunked remap within this z-plane. Plane size (Gx*Gy) is a multiple
    // of 8 in all launches, so plane-local lid%8 == hardware XCD round-robin.
    const int Gx = gridDim.x;
    if ((Gx & 7) == 0) {
        const int bnx = Gx >> 3;             // bn-columns per XCD (4 or 1)
        const int lid = bm * Gx + bn;
        const int xcd = lid & 7;
        const int ix  = lid >> 3;
        bn = xcd * bnx + (ix % bnx);
        bm = ix / bnx;
    }

    const int lane = tid & 63;
    const int wave = tid >> 6;
    const int wm   = wave >> 1, wn = wave & 1;
    const int lm   = lane & 15, lq = lane >> 4;

    const int K  = kchunk * S;
    const int k0 = kz * kchunk;

    const int rlo  = lane >> 3;                  // row within an 8-row staging chunk
    const int gsw8 = (((lane & 7) ^ rlo) << 3);  // swizzled granule -> element offset

    const __hip_bfloat16* Ag = A  + (size_t)(bm * 128) * K;
    const __hip_bfloat16* Bg = Bm + (size_t)(bn * 128) * K;

    // Issue prologue stage as early as possible (overlaps acc init).
    auto stage = [&](int d, int kt) {
        #pragma unroll
        for (int c = 0; c < 4; ++c) {
            const int chunk = wave * 4 + c;      // 0..15, wave-uniform
            const int row   = chunk * 8 + rlo;   // local tile row 0..127
            gload_lds16(Ag + (size_t)row * K + kt + gsw8, &As[d][chunk * 512]);
            gload_lds16(Bg + (size_t)row * K + kt + gsw8, &Bs[d][chunk * 512]);
        }
    };

    stage(0, k0);

    f32x4 acc[4][4];
    #pragma unroll
    for (int i = 0; i < 4; ++i)
        #pragma unroll
        for (int j = 0; j < 4; ++j)
            acc[i][j] = (f32x4){0.f, 0.f, 0.f, 0.f};

    auto compute = [&](int d) {
        #pragma unroll
        for (int kk = 0; kk < 2; ++kk) {
            // granule G = kk*4+lq of row lives at slot G^(row&7); row&7 == lm&7
            const int sl = (((kk * 4 + lq) ^ (lm & 7)) << 3);
            bf16x8 af[4], bq[4];
            #pragma unroll
            for (int i = 0; i < 4; ++i)
                af[i] = *(const bf16x8*)(&As[d][(wm * 64 + i * 16 + lm) * 64 + sl]);
            #pragma unroll
            for (int j = 0; j < 4; ++j)
                bq[j] = *(const bf16x8*)(&Bs[d][(wn * 64 + j * 16 + lm) * 64 + sl]);
            #pragma unroll
            for (int i = 0; i < 4; ++i)
                #pragma unroll
                for (int j = 0; j < 4; ++j)
                    acc[i][j] = __builtin_amdgcn_mfma_f32_16x16x32_bf16(af[i], bq[j], acc[i][j], 0, 0, 0);
        }
    };

    const int kend = k0 + kchunk;
    __syncthreads();                             // buf0 staged (barrier drains vmcnt)

    for (int kt = k0; kt < kend; kt += 128) {
        if (kt + 64 < kend) stage(1, kt + 64);   // prefetch overlaps compute(0)
        compute(0);
        __syncthreads();                         // drains vmcnt(0): buf1 ready, buf0 free
        if (kt + 64 < kend) {
            if (kt + 128 < kend) stage(0, kt + 128);
            compute(1);
            __syncthreads();
        }
    }

    __hip_bfloat16* Pz = P + (size_t)kz * M * N;
    const int row0 = bm * 128 + wm * 64;
    const int colb = bn * 128 + wn * 64 + lm;
    #pragma unroll
    for (int j = 0; j < 4; ++j) {
        const int col = colb + j * 16;
        #pragma unroll
        for (int i = 0; i < 4; ++i)
            #pragma unroll
            for (int r = 0; r < 4; ++r) {
                const int row = row0 + i * 16 + lq * 4 + r;
                Pz[(size_t)row * N + col] = __float2bfloat16(acc[i][j][r]);
            }
    }
}

// T-collapse: za = sum_{u=1..T} w_u * relu(c_u*y + b2), where
// c_u = 1-beta1^u, w_u = (1-b2f)(1-b3f)*g_u, g_u = b2f*g_{u+1} + b3f^(T-u), g_T=1.
// Exact algebra of the s2/za double recurrence; independent terms -> ILP.
template <int TT>
__device__ __forceinline__ void tcollapse_coef(float be1, float be2, float be3,
                                               float* __restrict__ c, float* __restrict__ w) {
    float g[TT + 1];
    g[TT] = 1.f;
    float p3 = 1.f;                      // beta3^(T-u), u descending
    #pragma unroll
    for (int u = TT - 1; u >= 1; --u) {
        p3 *= be3;
        g[u] = be2 * g[u + 1] + p3;
    }
    const float s = (1.f - be2) * (1.f - be3);
    float p1 = 1.f;
    #pragma unroll
    for (int u = 1; u <= TT; ++u) {
        p1 *= be1;
        c[u - 1] = 1.f - p1;
        w[u - 1] = s * g[u];
    }
}

// Sum S bf16 split-K partials (16B loads, fp32 accumulate) + epilogue. 8 elems/thread.
// MODE 0: bf16 out = relu(sum + bias)            (layer1 -> D1)
// MODE 1: bf16 out = T-collapse(y=sum, b2)       (layer2 -> Z)
// MODE 2: f32  out = sum + (1-beta3^T)*bias      (layer3 -> s3_T)
template <int MODE>
__global__ void reduce_k(const __hip_bfloat16* __restrict__ P, const int S,
                         void* __restrict__ outv, const long MN, const int N,
                         const float* __restrict__ bias,
                         const float* __restrict__ b_taus,
                         const int* __restrict__ Tp)
{
    long i8 = (long)blockIdx.x * 256 + threadIdx.x;   // 8-element group, exact cover
    long i  = i8 * 8;
    float a[8] = {0.f, 0.f, 0.f, 0.f, 0.f, 0.f, 0.f, 0.f};
    for (int s = 0; s < S; ++s) {
        union { s16x8 p8; __hip_bfloat16 h[8]; } u;
        u.p8 = *(const s16x8*)(P + (size_t)s * MN + i);
        #pragma unroll
        for (int c = 0; c < 8; ++c) a[c] += __bfloat162float(u.h[c]);
    }
    const int col = (int)(i % N);
    float bb[8];
    #pragma unroll
    for (int c = 0; c < 8; ++c) bb[c] = bias[col + c];

    if constexpr (MODE == 0) {
        union { s16x8 p8; __hip_bfloat16 h[8]; } u;
        #pragma unroll
        for (int c = 0; c < 8; ++c)
            u.h[c] = __float2bfloat16(fmaxf(a[c] + bb[c], 0.f));
        ((s16x8*)outv)[i8] = u.p8;
    } else if constexpr (MODE == 1) {
        const int   T   = *Tp;
        const float be1 = 1.f / (1.f + expf(-b_taus[0]));
        const float be2 = 1.f / (1.f + expf(-b_taus[1]));
        const float be3 = 1.f / (1.f + expf(-b_taus[2]));
        union { s16x8 p8; __hip_bfloat16 h[8]; } u;
        if (T == 10) {                     // fast path: fully unrolled, 10 independent terms
            float c10[10], w10[10];
            tcollapse_coef<10>(be1, be2, be3, c10, w10);
            #pragma unroll
            for (int c = 0; c < 8; ++c) {
                float za = 0.f;
                #pragma unroll
                for (int t = 0; t < 10; ++t)
                    za += w10[t] * fmaxf(fmaf(c10[t], a[c], bb[c]), 0.f);
                u.h[c] = __float2bfloat16(za);
            }
        } else {                           // generic fallback (original recurrence)
            #pragma unroll
            for (int c = 0; c < 8; ++c) {
                float p1 = 1.f, s2 = 0.f, za = 0.f;
                for (int t = 0; t < T; ++t) {
                    p1 *= be1;
                    const float d2 = fmaxf(fmaf(1.f - p1, a[c], bb[c]), 0.f);
                    s2 = be2 * s2 + (1.f - be2) * d2;
                    za = be3 * za + (1.f - be3) * s2;
                }
                u.h[c] = __float2bfloat16(za);
            }
        }
        ((s16x8*)outv)[i8] = u.p8;
    } else {
        const int   T   = *Tp;
        const float be3 = 1.f / (1.f + expf(-b_taus[2]));
        float g = 0.f;
        for (int t = 0; t < T; ++t) g = be3 * g + (1.f - be3);   // 1 - beta3^T
        f32x4 o0, o1;
        o0.x = a[0] + g * bb[0]; o0.y = a[1] + g * bb[1];
        o0.z = a[2] + g * bb[2]; o0.w = a[3] + g * bb[3];
        o1.x = a[4] + g * bb[4]; o1.y = a[5] + g * bb[5];
        o1.z = a[6] + g * bb[6]; o1.w = a[7] + g * bb[7];
        ((f32x4*)outv)[i8 * 2]     = o0;
        ((f32x4*)outv)[i8 * 2 + 1] = o1;
    }
}

extern "C" void kernel_launch(void* const* d_in, const int* in_sizes, int n_in,
                              void* d_out, int out_size, void* d_ws, size_t ws_size,
                              hipStream_t stream) {
    const float* x      = (const float*)d_in[0];
    const float* W1     = (const float*)d_in[1];
    const float* b1     = (const float*)d_in[2];
    const float* W2     = (const float*)d_in[3];
    const float* b2     = (const float*)d_in[4];
    const float* W3     = (const float*)d_in[5];
    const float* b3     = (const float*)d_in[6];
    const float* b_taus = (const float*)d_in[7];
    const int*   Tp     = (const int*)d_in[8];

    const int B = 1024, DIN = 2048, H1 = 4096, H2 = 4096, DOUT = 1024;
    const long MB = 1024 * 1024;

    // Arena (140 MB, no aliasing): xb 0, W1b 4, W2b 20, W3b 52, D1b 60, Sb 68,
    // P1 76 (16MB), P2 92 (now 16MB used), P3 124 (16MB)   [bf16 partials]
    char* ws = (char*)d_ws;
    __hip_bfloat16* xb  = (__hip_bfloat16*)(ws + 0);
    __hip_bfloat16* W1b = (__hip_bfloat16*)(ws + 4 * MB);
    __hip_bfloat16* W2b = (__hip_bfloat16*)(ws + 20 * MB);
    __hip_bfloat16* W3b = (__hip_bfloat16*)(ws + 52 * MB);
    __hip_bfloat16* D1b = (__hip_bfloat16*)(ws + 60 * MB);
    __hip_bfloat16* Sb  = (__hip_bfloat16*)(ws + 68 * MB);
    __hip_bfloat16* P1  = (__hip_bfloat16*)(ws + 76 * MB);
    __hip_bfloat16* P2  = (__hip_bfloat16*)(ws + 92 * MB);
    __hip_bfloat16* P3  = (__hip_bfloat16*)(ws + 124 * MB);

    // castA: x + W1 only (gates gemm1)
    cast_a_k<<<dim3(1280), dim3(256), 0, stream>>>(x, xb, W1, W1b);

    // Layer 1 GEMM (S=2) + 1 leading cast plane (W2/W3, 256 blocks = 1 slot/CU)
    gemm_btk<1><<<dim3(H1 / 128, B / 128, 1 + 2), 256, 0, stream>>>(
        xb, W1b, P1, B, H1, DIN / 2, 2,
        W2, W2b, (long)H2 * H1 / 8, W3, W3b, (long)DOUT * H2 / 8);
    reduce_k<0><<<dim3(2048), 256, 0, stream>>>(P1, 2, (void*)D1b, (long)B * H1, H1, b1, nullptr, nullptr);

    // Layer 2: S=2 (512 blocks = exactly one residency round at 2 blk/CU;
    // halves P2 partial traffic vs S=4)
    gemm_btk<0><<<dim3(H2 / 128, B / 128, 2), 256, 0, stream>>>(
        D1b, W2b, P2, B, H2, H1 / 2, 2, nullptr, nullptr, 0, nullptr, nullptr, 0);
    reduce_k<1><<<dim3(2048), 256, 0, stream>>>(P2, 2, (void*)Sb, (long)B * H2, H2, b2, b_taus, Tp);

    // Layer 3: S=8, 512 blocks
    gemm_btk<0><<<dim3(DOUT / 128, B / 128, 8), 256, 0, stream>>>(
        Sb, W3b, P3, B, DOUT, H2 / 8, 8, nullptr, nullptr, 0, nullptr, nullptr, 0);
    reduce_k<2><<<dim3(512), 256, 0, stream>>>(P3, 8, d_out, (long)B * DOUT, DOUT, b3, b_taus, Tp);
}